// Round 2
// 988.572 us; speedup vs baseline: 3.0461x; 3.0461x over previous
//
#include <hip/hip_runtime.h>

// Dims: B=16, H=W=64, C_OUT=64, C_IN=32, S(n_out)=10, 3x3 SAME conv adjoint.
// Input  w_out[b, 0, (h*64+w)*64+co, s] : per (b,pixel) contiguous 640 fp32 (co major, s minor)
// Output w_new[b, 0, (h*64+w)*32+ci, s] : per (b,pixel) contiguous 320 fp32 (ci major, s minor)
// y[b,s,h,w,ci] = sum_{i,j,co} z[b,s,h+1-i,w+1-j,co] * K[i,j,ci,co]
//
// Round-1 rewrite: the old kernel was L1-return-bandwidth bound (4B loaded per
// FMA-lane, all 32 ci lanes re-loading identical z => VALUBusy pinned at ~25%).
// Now: 8 ci per thread (80 accs), z staged in LDS and read with 4-way cig
// broadcast => 160 FMAs per 20 z-floats. LDS 70.7KB => 2 blocks/CU.
// (Round-2 resubmit: round-1 bench was an infra failure, kernel unchanged.)

typedef unsigned int uint;
typedef unsigned short ushort;

#define OUT_BU_OFF 20971520u   // 16*131072*10  (fp32 elements)
#define OUT_WL_OFF 20971680u
#define OUT_BL_OFF 41943200u
#define IN_PER_B   2621440u    // 4096*640 (fp32 elements)

__device__ __forceinline__ float bf_lo(uint u) { return __uint_as_float(u << 16); }
__device__ __forceinline__ float bf_hi(uint u) { return __uint_as_float(u & 0xffff0000u); }
__device__ __forceinline__ ushort f2bf(float f) {
    uint x = __float_as_uint(f);
    x += 0x7fffu + ((x >> 16) & 1u);   // RNE
    return (ushort)(x >> 16);
}

// ---------------- conv adjoint kernel ----------------
// grid: 2048 = 2 sets * 16 b * 64 h ; block: 256 = 64 w * 4 cig (tid = w*4+cig)
// Each thread: 1 pixel, ci0=cig*8 .. ci0+7, all 10 s  -> acc[80].
__global__ __launch_bounds__(256) void conv_kernel(
    const float* __restrict__ inU, const float* __restrict__ inL,
    const float* __restrict__ Kg, float* __restrict__ out)
{
    // [tap][cop][ci] -> packed pair (bf16(K[tap,ci,2cop]) | bf16(K[tap,ci,2cop+1])<<16)
    __shared__ uint  lk2[9 * 32 * 32];    // 36,864 B
    // z tile: [r(3 rows)][sw(64)][40 data + 4 pad floats]; stride 44 = 12 mod 32
    // => 2-way bank aliasing on strided reads (free), 16B-aligned rows.
    __shared__ float zlds[3 * 64 * 44];   // 33,792 B

    const int tid = threadIdx.x;

    for (int d = tid; d < 9 * 32 * 32; d += 256) {
        int tap = d >> 10;          // d / 1024
        int cop = (d >> 5) & 31;
        int ci  = d & 31;
        float k0 = Kg[tap * 2048 + ci * 64 + 2 * cop];
        float k1 = Kg[tap * 2048 + ci * 64 + 2 * cop + 1];
        lk2[tap * 1024 + cop * 32 + ci] = (uint)f2bf(k0) | ((uint)f2bf(k1) << 16);
    }

    // XCD-aware swizzle: physical blockIdx round-robins XCDs; remap so each XCD
    // owns a contiguous run of (set,b,h) => h-adjacent blocks share an L2.
    // 2048 % 8 == 0 => bijective.
    const int blk = (int)((blockIdx.x & 7) * 256 + (blockIdx.x >> 3));
    const int h   = blk & 63;
    const int b   = (blk >> 6) & 15;
    const int set = blk >> 10;

    const float* in   = set ? inL : inU;
    float*       outw = out + (set ? OUT_WL_OFF : 0u);

    const int cig = tid & 3;        // 0..3  -> ci0 = cig*8
    const int w   = tid >> 2;       // 0..63
    const int ci0 = cig * 8;
    const float* inb = in + (size_t)b * IN_PER_B;

    float acc[80];
#pragma unroll
    for (int t = 0; t < 80; ++t) acc[t] = 0.f;

    __syncthreads();    // lk2 visible (also covered by first stage barrier)

#pragma unroll 1
    for (int cb = 0; cb < 16; ++cb) {       // co-pair blocks: cop = cb*2 + {0,1}
        // ---- stage z[3 rows][64 w][40 floats] for this co-block ----
        // 1920 float4 loads, 256 threads, <=8 each; coalesced runs of 320B.
#pragma unroll
        for (int k = 0; k < 8; ++k) {
            int idx = tid + k * 256;
            if (idx < 1920) {
                int r   = idx / 640;
                int rem = idx - r * 640;
                int ww  = rem / 10;
                int c   = rem - ww * 10;
                int sh  = h - 1 + r;
                if ((unsigned)sh < 64u) {
                    const float4 v = *((const float4*)(inb + (size_t)(sh * 64 + ww) * 640u
                                                            + (size_t)cb * 40u) + c);
                    *(float4*)&zlds[(r * 64 + ww) * 44 + c * 4] = v;
                }
            }
        }
        __syncthreads();

        // ---- compute: taps x 2 co-pairs, 160 FMA per co-pair ----
#pragma unroll
        for (int i = 0; i < 3; ++i) {
            const int sh = h + 1 - i;               // block-uniform guard
            if ((unsigned)sh < 64u) {
                const int r = 2 - i;
#pragma unroll 1
                for (int j = 0; j < 3; ++j) {
                    const int sw = w + 1 - j;       // per-lane guard (<=4/64 lanes off)
                    if ((unsigned)sw < 64u) {
                        const float* zb = &zlds[(r * 64 + sw) * 44];
                        const uint*  kb = lk2 + (i * 3 + j) * 1024 + (cb * 2) * 32 + ci0;
#pragma unroll
                        for (int c4 = 0; c4 < 2; ++c4) {
                            const float4* q = (const float4*)(zb + c4 * 20);
                            float4 a0 = q[0], a1 = q[1], a2 = q[2], a3 = q[3], a4 = q[4];
                            const uint4* kq = (const uint4*)(kb + c4 * 32);
                            uint4 kA = kq[0], kB = kq[1];
                            const uint kk[8] = {kA.x, kA.y, kA.z, kA.w,
                                                kB.x, kB.y, kB.z, kB.w};
#pragma unroll
                            for (int cc = 0; cc < 8; ++cc) {
                                const float kf0 = bf_lo(kk[cc]);
                                const float kf1 = bf_hi(kk[cc]);
                                float* A = &acc[cc * 10];
                                A[0] += a0.x * kf0;  A[1] += a0.y * kf0;
                                A[2] += a0.z * kf0;  A[3] += a0.w * kf0;
                                A[4] += a1.x * kf0;  A[5] += a1.y * kf0;
                                A[6] += a1.z * kf0;  A[7] += a1.w * kf0;
                                A[8] += a2.x * kf0;  A[9] += a2.y * kf0;
                                A[0] += a2.z * kf1;  A[1] += a2.w * kf1;
                                A[2] += a3.x * kf1;  A[3] += a3.y * kf1;
                                A[4] += a3.z * kf1;  A[5] += a3.w * kf1;
                                A[6] += a4.x * kf1;  A[7] += a4.y * kf1;
                                A[8] += a4.z * kf1;  A[9] += a4.w * kf1;
                            }
                        }
                    }
                }
            }
        }
        __syncthreads();
    }

    // out[(b*131072 + (h*64+w)*32 + ci0)*10 ...]: 80 contiguous floats per thread,
    // consecutive tid => consecutive 320B chunks => fully contiguous per wave.
    const size_t obase = ((size_t)b * 131072u + (size_t)(h * 64 + w) * 32u + (size_t)ci0) * 10u;
    float4* op = (float4*)(outw + obase);
#pragma unroll
    for (int t = 0; t < 20; ++t)
        op[t] = make_float4(acc[4 * t], acc[4 * t + 1], acc[4 * t + 2], acc[4 * t + 3]);
}

// ---------------- bias-contribution partial reduction ----------------
// grid: 256 = 2 sets * 16 b * 8 pixel-chunks ; block: 640 threads (tid == co*10+s)
__global__ __launch_bounds__(640) void bias_kernel(
    const float* __restrict__ inU, const float* __restrict__ inL,
    const float* __restrict__ bias, float* __restrict__ ws)
{
    __shared__ float red[640];
    const int tid   = threadIdx.x;
    const int blk   = blockIdx.x;
    const int chunk = blk & 7;
    const int b     = (blk >> 3) & 15;
    const int set   = blk >> 7;

    const float* in = set ? inL : inU;
    const float  bf = bias[tid / 10];
    const float* p  = in + (size_t)b * IN_PER_B + (size_t)chunk * 512u * 640u;

    float acc = 0.f;
    for (int it = 0; it < 512; ++it) {
        acc += p[(size_t)it * 640u + tid] * bf;
    }
    red[tid] = acc;
    __syncthreads();

    if (tid < 10) {
        float t = 0.f;
        for (int co = 0; co < 64; ++co) t += red[co * 10 + tid];
        atomicAdd(&ws[(set * 16 + b) * 10 + tid], t);
    }
}

// ---------------- epilogue: add b_out, write fp32 ----------------
__global__ __launch_bounds__(320) void final_bias(
    const float* __restrict__ ws, const float* __restrict__ bU,
    const float* __restrict__ bL, float* __restrict__ out)
{
    const int i = threadIdx.x;
    if (i >= 320) return;
    const int set = i / 160;
    const int r   = i - set * 160;
    const float* bin = set ? bL : bU;
    out[(set ? OUT_BL_OFF : OUT_BU_OFF) + r] = ws[i] + bin[r];
}

extern "C" void kernel_launch(void* const* d_in, const int* in_sizes, int n_in,
                              void* d_out, int out_size, void* d_ws, size_t ws_size,
                              hipStream_t stream) {
    const float* wU   = (const float*)d_in[0];
    const float* bU   = (const float*)d_in[1];
    const float* wL   = (const float*)d_in[2];
    const float* bL   = (const float*)d_in[3];
    const float* Kg   = (const float*)d_in[4];
    const float* bias = (const float*)d_in[5];
    float* out = (float*)d_out;
    float* ws  = (float*)d_ws;

    hipMemsetAsync(ws, 0, 320 * sizeof(float), stream);
    hipLaunchKernelGGL(bias_kernel, dim3(256), dim3(640), 0, stream, wU, wL, bias, ws);
    hipLaunchKernelGGL(conv_kernel, dim3(2048), dim3(256), 0, stream, wU, wL, Kg, out);
    hipLaunchKernelGGL(final_bias, dim3(1), dim3(320), 0, stream, ws, bU, bL, out);
}

// Round 3
// 855.112 us; speedup vs baseline: 3.5215x; 1.1561x over previous
//
#include <hip/hip_runtime.h>

// Dims: B=16, H=W=64, C_OUT=64, C_IN=32, S(n_out)=10, 3x3 SAME conv adjoint.
// Input  w_out[b, 0, (h*64+w)*64+co, s] : per (b,pixel) contiguous 640 fp32 (co major, s minor)
// Output w_new[b, 0, (h*64+w)*32+ci, s] : per (b,pixel) contiguous 320 fp32 (ci major, s minor)
// y[b,s,h,w,ci] = sum_{i,j,co} z[b,s,h+1-i,w+1-j,co] * K[i,j,ci,co]
//
// Round-3: (a) z double-buffered (half co-tile: 20 floats/pixel/iter, 32 iters),
// reg-staged with loads issued one full compute-phase early (T14) and ONE
// barrier per iter; (b) bias contribution fused into conv (center row r=1 is
// staged exactly once per block) -> bias_kernel deleted, its 335MB re-read gone.

typedef unsigned int uint;
typedef unsigned short ushort;

#define OUT_BU_OFF 20971520u   // 16*131072*10  (fp32 elements)
#define OUT_WL_OFF 20971680u
#define OUT_BL_OFF 41943200u
#define IN_PER_B   2621440u    // 4096*640 (fp32 elements)

__device__ __forceinline__ float bf_lo(uint u) { return __uint_as_float(u << 16); }
__device__ __forceinline__ float bf_hi(uint u) { return __uint_as_float(u & 0xffff0000u); }
__device__ __forceinline__ ushort f2bf(float f) {
    uint x = __float_as_uint(f);
    x += 0x7fffu + ((x >> 16) & 1u);   // RNE
    return (ushort)(x >> 16);
}

// grid: 2048 = 2 sets * 16 b * 64 h ; block: 256 = 64 w * 4 cig (tid = w*4+cig)
// Each thread: 1 pixel, ci0=cig*8 .. ci0+7, all 10 s -> acc[80].
// Loop over t=0..31 (co-pair index cop=t; co = 2t,2t+1 = 20 floats/pixel/iter).
__global__ __launch_bounds__(256) void conv_kernel(
    const float* __restrict__ inU, const float* __restrict__ inL,
    const float* __restrict__ Kg, const float* __restrict__ bias,
    float* __restrict__ out, float* __restrict__ ws)
{
    // [tap][cop][ci] -> packed (bf16(K[tap,ci,2cop]) | bf16(K[tap,ci,2cop+1])<<16)
    __shared__ uint  lk2[9 * 32 * 32];   // 36,864 B
    // double-buffered z: [buf][r*64+ww][20]; stride 20 => 2-way bank alias (free)
    __shared__ float zl[2 * 3840];       // 30,720 B
    __shared__ float red[1280];          // 5,120 B (bias block-reduction)
    __shared__ float blds[64];           // 256 B
    // total 72,960 B -> 2 blocks/CU

    const int tid = threadIdx.x;

    for (int d = tid; d < 9 * 32 * 32; d += 256) {
        int tap = d >> 10;
        int cop = (d >> 5) & 31;
        int ci  = d & 31;
        float k0 = Kg[tap * 2048 + ci * 64 + 2 * cop];
        float k1 = Kg[tap * 2048 + ci * 64 + 2 * cop + 1];
        lk2[tap * 1024 + cop * 32 + ci] = (uint)f2bf(k0) | ((uint)f2bf(k1) << 16);
    }
    if (tid < 64) blds[tid] = bias[tid];

    // XCD-aware bijective swizzle (2048 % 8 == 0)
    const int blk = (int)((blockIdx.x & 7) * 256 + (blockIdx.x >> 3));
    const int h   = blk & 63;
    const int b   = (blk >> 6) & 15;
    const int set = blk >> 10;

    const float* in   = set ? inL : inU;
    float*       outw = out + (set ? OUT_WL_OFF : 0u);
    const float* inb  = in + (size_t)b * IN_PER_B;

    const int cig = tid & 3;
    const int w   = tid >> 2;
    const int ci0 = cig * 8;

    // ---- staging slots: 960 float4 chunks = 3 rows * 64 ww * 5 c ----
    int gof[4], lof[4]; bool ok[4];
#pragma unroll
    for (int u = 0; u < 4; ++u) {
        int m  = tid + u * 256;
        int r  = m / 320;
        int mm = m - r * 320;
        int ww = mm / 5;
        int c  = mm - ww * 5;
        int sh = h - 1 + r;
        ok[u]  = (m < 960) && ((unsigned)sh < 64u);
        gof[u] = (sh * 64 + ww) * 640 + c * 4;   // + t*20 per iter
        lof[u] = (r * 64 + ww) * 20 + c * 4;
    }

#define LOADV(T) do { \
        if (ok[0]) v0 = *(const float4*)(inb + gof[0] + (T) * 20); \
        if (ok[1]) v1 = *(const float4*)(inb + gof[1] + (T) * 20); \
        if (ok[2]) v2 = *(const float4*)(inb + gof[2] + (T) * 20); \
        if (ok[3]) v3 = *(const float4*)(inb + gof[3] + (T) * 20); \
    } while (0)
#define STOREV(BUF) do { \
        float* zb_ = &zl[(BUF) * 3840]; \
        if (ok[0]) *(float4*)(zb_ + lof[0]) = v0; \
        if (ok[1]) *(float4*)(zb_ + lof[1]) = v1; \
        if (ok[2]) *(float4*)(zb_ + lof[2]) = v2; \
        if (ok[3]) *(float4*)(zb_ + lof[3]) = v3; \
    } while (0)

    float acc[80];
#pragma unroll
    for (int q = 0; q < 80; ++q) acc[q] = 0.f;
    float ab0 = 0.f, ab1 = 0.f, ab2 = 0.f, ab3 = 0.f, ab4 = 0.f;

    float4 v0, v1, v2, v3;
    LOADV(0);
    __syncthreads();            // lk2 + blds visible
    STOREV(0);
    LOADV(1);
    __syncthreads();            // buf0 ready

#pragma unroll 1
    for (int t = 0; t < 32; ++t) {
        const int cur = t & 1;
        if (t < 31) {
            STOREV(cur ^ 1);    // buf^1 last read at iter t-1; barrier protects
            if (t < 30) LOADV(t + 2);   // in flight across this whole compute
        }

        const float* zbase = &zl[cur * 3840];
        const uint*  lkb   = lk2 + t * 32 + ci0;

#pragma unroll
        for (int i = 0; i < 3; ++i) {
            const int sh = h + 1 - i;           // block-uniform guard
            if ((unsigned)sh < 64u) {
                const int r = 2 - i;
#pragma unroll 1
                for (int j = 0; j < 3; ++j) {
                    const int sw = w + 1 - j;   // per-lane guard
                    if ((unsigned)sw < 64u) {
                        const float* zb = zbase + (r * 64 + sw) * 20;
                        const uint*  kp = lkb + (i * 3 + j) * 1024;
                        float4 a0 = ((const float4*)zb)[0], a1 = ((const float4*)zb)[1],
                               a2 = ((const float4*)zb)[2], a3 = ((const float4*)zb)[3],
                               a4 = ((const float4*)zb)[4];
                        uint4 kA = ((const uint4*)kp)[0], kB = ((const uint4*)kp)[1];
                        const uint kk[8] = {kA.x, kA.y, kA.z, kA.w,
                                            kB.x, kB.y, kB.z, kB.w};
#pragma unroll
                        for (int cc = 0; cc < 8; ++cc) {
                            const float kf0 = bf_lo(kk[cc]);
                            const float kf1 = bf_hi(kk[cc]);
                            float* A = &acc[cc * 10];
                            A[0] += a0.x * kf0;  A[1] += a0.y * kf0;
                            A[2] += a0.z * kf0;  A[3] += a0.w * kf0;
                            A[4] += a1.x * kf0;  A[5] += a1.y * kf0;
                            A[6] += a1.z * kf0;  A[7] += a1.w * kf0;
                            A[8] += a2.x * kf0;  A[9] += a2.y * kf0;
                            A[0] += a2.z * kf1;  A[1] += a2.w * kf1;
                            A[2] += a3.x * kf1;  A[3] += a3.y * kf1;
                            A[4] += a3.z * kf1;  A[5] += a3.w * kf1;
                            A[6] += a4.x * kf1;  A[7] += a4.y * kf1;
                            A[8] += a4.z * kf1;  A[9] += a4.w * kf1;
                        }
                    }
                }
            }
        }

        // ---- fused bias: center row r=1 == input row h, staged exactly once ----
        // thread (w,cig): co = 2t + (cig>>1), s = (cig&1)*5 + u, fp32-exact z
        {
            const float  bf = blds[2 * t + (cig >> 1)];
            const float* zc = zbase + (64 + w) * 20 + cig * 5;
            ab0 += zc[0] * bf;  ab1 += zc[1] * bf;  ab2 += zc[2] * bf;
            ab3 += zc[3] * bf;  ab4 += zc[4] * bf;
        }

        __syncthreads();        // one barrier per iter
    }

    // ---- output: 80 contiguous floats per thread, contiguous per wave ----
    const size_t obase = ((size_t)b * 131072u + (size_t)(h * 64 + w) * 32u + (size_t)ci0) * 10u;
    float4* op = (float4*)(outw + obase);
#pragma unroll
    for (int q = 0; q < 20; ++q)
        op[q] = make_float4(acc[4 * q], acc[4 * q + 1], acc[4 * q + 2], acc[4 * q + 3]);

    // ---- bias block-reduction: s = (cig&1)*5 + u ----
    red[tid * 5 + 0] = ab0;  red[tid * 5 + 1] = ab1;  red[tid * 5 + 2] = ab2;
    red[tid * 5 + 3] = ab3;  red[tid * 5 + 4] = ab4;
    __syncthreads();
    if (tid < 10) {
        const int u  = tid % 5;
        const int cg = tid / 5;             // cig&1
        float sum = 0.f;
#pragma unroll 4
        for (int q = 0; q < 128; ++q) {
            int ww   = q >> 1;
            int half = q & 1;               // cig = cg + 2*half
            sum += red[(ww * 4 + cg + 2 * half) * 5 + u];
        }
        atomicAdd(&ws[(set * 16 + b) * 10 + tid], sum);
    }
#undef LOADV
#undef STOREV
}

// ---------------- epilogue: add b_out, write fp32 ----------------
__global__ __launch_bounds__(320) void final_bias(
    const float* __restrict__ ws, const float* __restrict__ bU,
    const float* __restrict__ bL, float* __restrict__ out)
{
    const int i = threadIdx.x;
    if (i >= 320) return;
    const int set = i / 160;
    const int r   = i - set * 160;
    const float* bin = set ? bL : bU;
    out[(set ? OUT_BL_OFF : OUT_BU_OFF) + r] = ws[i] + bin[r];
}

extern "C" void kernel_launch(void* const* d_in, const int* in_sizes, int n_in,
                              void* d_out, int out_size, void* d_ws, size_t ws_size,
                              hipStream_t stream) {
    const float* wU   = (const float*)d_in[0];
    const float* bU   = (const float*)d_in[1];
    const float* wL   = (const float*)d_in[2];
    const float* bL   = (const float*)d_in[3];
    const float* Kg   = (const float*)d_in[4];
    const float* bias = (const float*)d_in[5];
    float* out = (float*)d_out;
    float* ws  = (float*)d_ws;

    hipMemsetAsync(ws, 0, 320 * sizeof(float), stream);
    hipLaunchKernelGGL(conv_kernel, dim3(2048), dim3(256), 0, stream,
                       wU, wL, Kg, bias, out, ws);
    hipLaunchKernelGGL(final_bias, dim3(1), dim3(320), 0, stream, ws, bU, bL, out);
}